// Round 6
// baseline (139.104 us; speedup 1.0000x reference)
//
#include <hip/hip_runtime.h>
#include <hip/hip_bf16.h>

// Problem: B=4, N=2048, C=512, H=8, D=64, L=64, SCALE=0.125. Inputs f32, output f32.
// No softmax => attention is linear => reassociate:
//   out[b] = (x[b]@Wq * SCALE)(2048x512) @ Wcat[b](512x64)
//   Wcat[b][h*64+dq][:] = ( sum_m k[b,m,h,dq] * v[m,h,:] ) @ proj_h
// R6: KV and W computed by MFMA from transposed K/V/proj layouts; no partials buffer.

using f32x4 = __attribute__((ext_vector_type(4))) float;
using s16x8 = __attribute__((ext_vector_type(8))) short;  // 8 bf16 (4 VGPRs), MFMA operand

__device__ __forceinline__ unsigned short f2bf(float f) {
  unsigned int i;
  __builtin_memcpy(&i, &f, 4);
  unsigned int lsb = (i >> 16) & 1u;
  i += 0x7fffu + lsb;  // round-to-nearest-even
  return (unsigned short)(i >> 16);
}
__device__ __forceinline__ ushort4 pk4(f32x4 a) {
  ushort4 u;
  u.x = f2bf(a[0]); u.y = f2bf(a[1]); u.z = f2bf(a[2]); u.w = f2bf(a[3]);
  return u;
}
__device__ __forceinline__ void async_cp16(const void* g, void* l) {
  // 16B global->LDS DMA; LDS dest must be WAVE-UNIFORM base (HW adds lane*16)
  __builtin_amdgcn_global_load_lds((const __attribute__((address_space(1))) void*)g,
                                   (__attribute__((address_space(3))) void*)l, 16, 0, 0);
}

// ---------------- 1) prep: x convert (0..2047) | qkv T (2048..2559) | v T (2560..3583) | proj T (3584..3615)
__global__ void k_prep(const float* __restrict__ x, const float* __restrict__ qkv,
                       const float* __restrict__ v, const float* __restrict__ proj,
                       unsigned short* __restrict__ xb, unsigned short* __restrict__ qkvT,
                       unsigned short* __restrict__ VT, unsigned short* __restrict__ projT) {
  const int id = blockIdx.x;
  const int tid = threadIdx.x;
  if (id < 2048) {
    size_t i = ((size_t)id * 256 + tid) * 8;
    f32x4 a = *(const f32x4*)(x + i);
    f32x4 b = *(const f32x4*)(x + i + 4);
    ushort4 lo, hi;
    lo.x = f2bf(a[0]); lo.y = f2bf(a[1]); lo.z = f2bf(a[2]); lo.w = f2bf(a[3]);
    hi.x = f2bf(b[0]); hi.y = f2bf(b[1]); hi.z = f2bf(b[2]); hi.w = f2bf(b[3]);
    *(ushort4*)(xb + i) = lo;
    *(ushort4*)(xb + i + 4) = hi;
    return;
  }
  __shared__ float tile[32][33];
  const int tx = tid & 31, ty = tid >> 5;  // 32 x 8
  if (id < 2560) {
    // qkvT[s*512+h*64+d][c] = qkv[c][h*128+s*64+d]
    const int idx = id - 2048;
    const int j0 = (idx & 31) * 32;
    const int c0 = (idx >> 5) * 32;
#pragma unroll
    for (int i = 0; i < 32; i += 8)
      tile[ty + i][tx] = qkv[(size_t)(c0 + ty + i) * 1024 + j0 + tx];
    __syncthreads();
    const int h = j0 >> 7, s = (j0 >> 6) & 1, d0 = j0 & 63;
    const int jp0 = s * 512 + h * 64 + d0;
#pragma unroll
    for (int i = 0; i < 32; i += 8)
      qkvT[(size_t)(jp0 + ty + i) * 512 + c0 + tx] = f2bf(tile[tx][ty + i]);
  } else if (id < 3584) {
    // VT[h*64+l][n] = v[n][h*64+l]
    const int idx = id - 2560;
    const int j0 = (idx & 15) * 32;
    const int n0 = (idx >> 4) * 32;
#pragma unroll
    for (int i = 0; i < 32; i += 8)
      tile[ty + i][tx] = v[(size_t)(n0 + ty + i) * 512 + j0 + tx];
    __syncthreads();
#pragma unroll
    for (int i = 0; i < 32; i += 8)
      VT[(size_t)(j0 + ty + i) * 2048 + n0 + tx] = f2bf(tile[tx][ty + i]);
  } else {
    // projT[dout][h*64+l] = proj[h*64+l][dout]
    const int idx = id - 3584;
    const int d0 = (idx & 1) * 32;
    const int j0 = (idx >> 1) * 32;
#pragma unroll
    for (int i = 0; i < 32; i += 8)
      tile[ty + i][tx] = proj[(size_t)(j0 + ty + i) * 64 + d0 + tx];
    __syncthreads();
#pragma unroll
    for (int i = 0; i < 32; i += 8)
      projT[(size_t)(d0 + ty + i) * 512 + j0 + tx] = f2bf(tile[tx][ty + i]);
  }
}

// ---------------- 2) GEMM1 (8 waves, XCD-swizzled): xb @ qkvT^T -> Q (row-major, scaled), K (transposed)
__global__ __launch_bounds__(512) void k_gemm1(
    const unsigned short* __restrict__ A,    // xb [8192][512] bf16
    const unsigned short* __restrict__ Bt,   // qkvT [1024][512] bf16
    unsigned short* __restrict__ Qws,        // [8192][512] col = h*64+d
    unsigned short* __restrict__ KwsT) {     // [(b*8+h)*64+d][2048]
  __shared__ unsigned short As[128 * 64];
  __shared__ unsigned short Bs[128 * 64];
  const int lin = blockIdx.x;
  const int wg = (lin & 7) * 64 + (lin >> 3);   // bijective: 512 = 8 XCDs x 64
  const int m0 = (wg >> 3) * 128;
  const int n0 = (wg & 7) * 128;
  const int tid = threadIdx.x;
  const int lane = tid & 63;
  const int wave = tid >> 6;       // 8 waves: wm 4 x wn 2
  const int wm = wave >> 1, wn = wave & 1;

  f32x4 acc[2][4] = {};

  const int rlane = lane >> 3;        // row within wave's 8-row stage group
  const int clane = (lane & 7) * 8;   // 8 bf16 = 16B

  for (int kt = 0; kt < 512; kt += 64) {
    __syncthreads();
#pragma unroll
    for (int i = 0; i < 2; ++i) {
      async_cp16(A + (size_t)(m0 + i * 64 + wave * 8 + rlane) * 512 + kt + clane,
                 As + (i * 64 + wave * 8) * 64);
      async_cp16(Bt + (size_t)(n0 + i * 64 + wave * 8 + rlane) * 512 + kt + clane,
                 Bs + (i * 64 + wave * 8) * 64);
    }
    __syncthreads();
#pragma unroll
    for (int kk = 0; kk < 64; kk += 32) {
      s16x8 af[2], bfr[4];
#pragma unroll
      for (int i = 0; i < 2; ++i)
        af[i] = *(const s16x8*)(As + (wm * 32 + i * 16 + (lane & 15)) * 64 + kk + (lane >> 4) * 8);
#pragma unroll
      for (int j = 0; j < 4; ++j)
        bfr[j] = *(const s16x8*)(Bs + (wn * 64 + j * 16 + (lane & 15)) * 64 + kk + (lane >> 4) * 8);
#pragma unroll
      for (int i = 0; i < 2; ++i)
#pragma unroll
        for (int j = 0; j < 4; ++j)
          acc[i][j] = __builtin_amdgcn_mfma_f32_16x16x32_bf16(af[i], bfr[j], acc[i][j], 0, 0, 0);
    }
  }
  const int n_base = n0 + wn * 64;
  if (n_base < 512) {
    // Q wave: row-major store, fold SCALE=0.125 (exact pow2)
#pragma unroll
    for (int i = 0; i < 2; ++i) {
      int grow = m0 + wm * 32 + i * 16 + (lane >> 4) * 4;
#pragma unroll
      for (int j = 0; j < 4; ++j) {
        int gcol = n_base + j * 16 + (lane & 15);
#pragma unroll
        for (int r = 0; r < 4; ++r)
          Qws[(size_t)(grow + r) * 512 + gcol] = f2bf(acc[i][j][r] * 0.125f);
      }
    }
  } else {
    // K wave: transposed store KwsT[(b*8+h)*64+d][n]; 4 consecutive rows pack to one 8B store
#pragma unroll
    for (int i = 0; i < 2; ++i) {
      int grow = m0 + wm * 32 + i * 16 + (lane >> 4) * 4;
      int b = grow >> 11, n = grow & 2047;
#pragma unroll
      for (int j = 0; j < 4; ++j) {
        int dfull = n_base - 512 + j * 16 + (lane & 15);   // h*64+d
        *(ushort4*)(KwsT + (size_t)(b * 512 + dfull) * 2048 + n) = pk4(acc[i][j]);
      }
    }
  }
}

// ---------------- 3) KV + W fused (MFMA): per (b,h): KV = KwsT_slice @ VT_slice^T; W = KV @ projT^T
__global__ __launch_bounds__(256) void k_kv_w(
    const unsigned short* __restrict__ KwsT,   // [(b*8+h)*64+d][2048]
    const unsigned short* __restrict__ VT,     // [h*64+l][2048]
    const unsigned short* __restrict__ projT,  // [dout][h*64+l]
    unsigned short* __restrict__ WcatT) {      // [b*64+dout][h*64+dq]
  const int bh = blockIdx.x;  // b*8 + h
  const int h = bh & 7;
  const int b = bh >> 3;
  const int tid = threadIdx.x;
  const int lane = tid & 63;
  const int wave = tid >> 6;             // 4 waves x 16 rows
  const int arow = wave * 16 + (lane & 15);
  const int koff = (lane >> 4) * 8;
  const unsigned short* Ab = KwsT + (size_t)bh * 64 * 2048;  // rows = dq
  const unsigned short* Bb = VT + (size_t)h * 64 * 2048;     // rows = l (mfma cols)

  f32x4 acc[4] = {};
#pragma unroll 4
  for (int kk = 0; kk < 64; ++kk) {
    s16x8 af = *(const s16x8*)(Ab + (size_t)arow * 2048 + kk * 32 + koff);
#pragma unroll
    for (int j = 0; j < 4; ++j) {
      s16x8 bf = *(const s16x8*)(Bb + (size_t)(j * 16 + (lane & 15)) * 2048 + kk * 32 + koff);
      acc[j] = __builtin_amdgcn_mfma_f32_16x16x32_bf16(af, bf, acc[j], 0, 0, 0);
    }
  }
  // KV frags -> LDS as bf16 (rows=dq, cols=l), padded rows for bank spread
  __shared__ unsigned short kvl[64][80];
#pragma unroll
  for (int j = 0; j < 4; ++j) {
    int row = wave * 16 + (lane >> 4) * 4;
    int col = j * 16 + (lane & 15);
#pragma unroll
    for (int r = 0; r < 4; ++r)
      kvl[row + r][col] = f2bf(acc[j][r]);
  }
  __syncthreads();
  // W = KV(64x64) @ projT^T : rows=dq, cols=dout, k=l
  f32x4 wacc[4] = {};
#pragma unroll
  for (int kk = 0; kk < 2; ++kk) {
    s16x8 af = *(const s16x8*)(&kvl[arow][kk * 32 + koff]);
#pragma unroll
    for (int j = 0; j < 4; ++j) {
      s16x8 bf = *(const s16x8*)(projT + (size_t)(j * 16 + (lane & 15)) * 512 + h * 64 + kk * 32 + koff);
      wacc[j] = __builtin_amdgcn_mfma_f32_16x16x32_bf16(af, bf, wacc[j], 0, 0, 0);
    }
  }
  const int dq = wave * 16 + (lane >> 4) * 4;
#pragma unroll
  for (int j = 0; j < 4; ++j) {
    int dout = j * 16 + (lane & 15);
    *(ushort4*)(WcatT + (size_t)(b * 64 + dout) * 512 + h * 64 + dq) = pk4(wacc[j]);
  }
}

// ---------------- 4) GEMM2 streaming: out[b] = Qws[b](2048x512) @ WcatT[b]^T(512x64)
__global__ __launch_bounds__(64) void k_gemm2(
    const unsigned short* __restrict__ Qws,
    const unsigned short* __restrict__ WcatT,
    float* __restrict__ out) {   // [8192][64] f32
  const int m0 = blockIdx.x * 16;
  const int lane = threadIdx.x;
  const unsigned short* Bb = WcatT + (size_t)(m0 >> 11) * 64 * 512;
  const int arow = lane & 15;
  const int koff = (lane >> 4) * 8;
  f32x4 acc[4] = {};
#pragma unroll
  for (int kk = 0; kk < 16; ++kk) {
    s16x8 af = *(const s16x8*)(Qws + (size_t)(m0 + arow) * 512 + kk * 32 + koff);
#pragma unroll
    for (int j = 0; j < 4; ++j) {
      s16x8 bf = *(const s16x8*)(Bb + (size_t)(j * 16 + arow) * 512 + kk * 32 + koff);
      acc[j] = __builtin_amdgcn_mfma_f32_16x16x32_bf16(af, bf, acc[j], 0, 0, 0);
    }
  }
  const int grow = m0 + (lane >> 4) * 4;
#pragma unroll
  for (int j = 0; j < 4; ++j) {
    int gcol = j * 16 + arow;
#pragma unroll
    for (int r = 0; r < 4; ++r)
      out[(size_t)(grow + r) * 64 + gcol] = acc[j][r];
  }
}

extern "C" void kernel_launch(void* const* d_in, const int* in_sizes, int n_in,
                              void* d_out, int out_size, void* d_ws, size_t ws_size,
                              hipStream_t stream) {
  const float* x    = (const float*)d_in[0];  // [4][2048][512] f32
  const float* v    = (const float*)d_in[1];  // [2048][8][64]  f32
  const float* qkv  = (const float*)d_in[2];  // [512][1024]    f32
  const float* proj = (const float*)d_in[3];  // [512][64]      f32
  float* out = (float*)d_out;                 // [4][2048][64]  f32

  char* ws = (char*)d_ws;
  unsigned short* xb    = (unsigned short*)ws; ws += (size_t)8192 * 512 * 2;  // 8.4 MB
  unsigned short* qkvT  = (unsigned short*)ws; ws += (size_t)1024 * 512 * 2;  // 1 MB
  unsigned short* Qws   = (unsigned short*)ws; ws += (size_t)8192 * 512 * 2;  // 8.4 MB
  unsigned short* KwsT  = (unsigned short*)ws; ws += (size_t)8192 * 512 * 2;  // 8.4 MB
  unsigned short* VT    = (unsigned short*)ws; ws += (size_t)512 * 2048 * 2;  // 2 MB
  unsigned short* projT = (unsigned short*)ws; ws += (size_t)64 * 512 * 2;    // 64 KB
  unsigned short* Wc    = (unsigned short*)ws; ws += (size_t)4 * 64 * 512 * 2;

  hipLaunchKernelGGL(k_prep, dim3(3616), dim3(256), 0, stream, x, qkv, v, proj, xb, qkvT, VT, projT);
  hipLaunchKernelGGL(k_gemm1, dim3(512), dim3(512), 0, stream, xb, qkvT, Qws, KwsT);
  hipLaunchKernelGGL(k_kv_w, dim3(32), dim3(256), 0, stream, KwsT, VT, projT, Wc);
  hipLaunchKernelGGL(k_gemm2, dim3(512), dim3(64), 0, stream, Qws, Wc, out);
}

// Round 7
// 123.450 us; speedup vs baseline: 1.1268x; 1.1268x over previous
//
#include <hip/hip_runtime.h>
#include <hip/hip_bf16.h>

// Problem: B=4, N=2048, C=512, H=8, D=64, L=64, SCALE=0.125. Inputs f32, output f32.
// No softmax => attention is linear => reassociate:
//   out[b] = (x[b]@Wq * SCALE)(2048x512) @ Wcat[b](512x64)
//   Wcat[b][h*64+dq][:] = ( sum_m k[b,m,h,dq] * v[m,h,:] ) @ proj_h
// R7 = R5 (best measured) + gemm1 BK=128 (half the barrier drains, same occupancy).

using f32x4 = __attribute__((ext_vector_type(4))) float;
using s16x8 = __attribute__((ext_vector_type(8))) short;  // 8 bf16 (4 VGPRs), MFMA operand

__device__ __forceinline__ unsigned short f2bf(float f) {
  unsigned int i;
  __builtin_memcpy(&i, &f, 4);
  unsigned int lsb = (i >> 16) & 1u;
  i += 0x7fffu + lsb;  // round-to-nearest-even
  return (unsigned short)(i >> 16);
}
__device__ __forceinline__ float bf2f(unsigned short u) {
  unsigned int i = ((unsigned int)u) << 16;
  float f;
  __builtin_memcpy(&f, &i, 4);
  return f;
}
__device__ __forceinline__ void async_cp16(const void* g, void* l) {
  // 16B global->LDS DMA; LDS dest must be WAVE-UNIFORM base (HW adds lane*16)
  __builtin_amdgcn_global_load_lds((const __attribute__((address_space(1))) void*)g,
                                   (__attribute__((address_space(3))) void*)l, 16, 0, 0);
}

// ---------------- 1) prep: convert x f32->bf16 (blocks 0..2047), transpose qkv (2048..2559)
__global__ void k_prep(const float* __restrict__ x, const float* __restrict__ qkv,
                       unsigned short* __restrict__ xb, unsigned short* __restrict__ qkvT) {
  const int id = blockIdx.x;
  const int tid = threadIdx.x;
  if (id < 2048) {
    size_t i = ((size_t)id * 256 + tid) * 8;
    f32x4 a = *(const f32x4*)(x + i);
    f32x4 b = *(const f32x4*)(x + i + 4);
    ushort4 lo, hi;
    lo.x = f2bf(a[0]); lo.y = f2bf(a[1]); lo.z = f2bf(a[2]); lo.w = f2bf(a[3]);
    hi.x = f2bf(b[0]); hi.y = f2bf(b[1]); hi.z = f2bf(b[2]); hi.w = f2bf(b[3]);
    *(ushort4*)(xb + i) = lo;
    *(ushort4*)(xb + i + 4) = hi;
  } else {
    // qkvT[s*512+h*64+d][c] = qkv[c][h*128+s*64+d]
    __shared__ float tile[32][33];
    const int idx = id - 2048;
    const int j0 = (idx & 31) * 32;
    const int c0 = (idx >> 5) * 32;
    const int tx = tid & 31, ty = tid >> 5;  // 32 x 8
#pragma unroll
    for (int i = 0; i < 32; i += 8)
      tile[ty + i][tx] = qkv[(size_t)(c0 + ty + i) * 1024 + j0 + tx];
    __syncthreads();
    const int h = j0 >> 7, s = (j0 >> 6) & 1, d0 = j0 & 63;
    const int jp0 = s * 512 + h * 64 + d0;
#pragma unroll
    for (int i = 0; i < 32; i += 8)
      qkvT[(size_t)(jp0 + ty + i) * 512 + c0 + tx] = f2bf(tile[tx][ty + i]);
  }
}

// ---------------- 2) GEMM1 (8 waves, BK=128, XCD-swizzled): xb @ qkvT^T -> Q (scaled), K
// Grid 512 linear. Swizzle: XCD k owns wg [k*64,(k+1)*64) = 8 m-panels x all 8 n-panels,
// so per-XCD working set (2MB A-panels + 1MB B) fits the 4MB XCD L2.
// BK=128: LDS 64KB -> still exactly 2 blocks/CU (grid-pinned); barriers 16 -> 8.
__global__ __launch_bounds__(512) void k_gemm1(
    const unsigned short* __restrict__ A,   // xb [8192][512] bf16
    const unsigned short* __restrict__ Bt,  // qkvT [1024][512] bf16
    unsigned short* __restrict__ Qws,       // [8192][512] col = h*64+d
    unsigned short* __restrict__ Kws) {     // [8192][512]
  __shared__ unsigned short As[128 * 128];  // 32KB
  __shared__ unsigned short Bs[128 * 128];  // 32KB
  const int lin = blockIdx.x;
  const int wg = (lin & 7) * 64 + (lin >> 3);   // bijective: 512 = 8 XCDs x 64
  const int m0 = (wg >> 3) * 128;
  const int n0 = (wg & 7) * 128;
  const int tid = threadIdx.x;
  const int lane = tid & 63;
  const int wave = tid >> 6;       // 8 waves: wm 4 x wn 2
  const int wm = wave >> 1, wn = wave & 1;

  f32x4 acc[2][4] = {};

  const int rlane = lane >> 4;        // 0..3: row within wave's 4-row stage group
  const int clane = (lane & 15) * 8;  // 16 lanes x 8 bf16 = 128 cols (256B row)

  for (int kt = 0; kt < 512; kt += 128) {
    __syncthreads();
    // one call: 512 thr x 16B = 8KB = 32 rows of 256B; 4 calls each for A and B
#pragma unroll
    for (int i = 0; i < 4; ++i) {
      async_cp16(A + (size_t)(m0 + i * 32 + wave * 4 + rlane) * 512 + kt + clane,
                 As + (i * 32 + wave * 4) * 128);
      async_cp16(Bt + (size_t)(n0 + i * 32 + wave * 4 + rlane) * 512 + kt + clane,
                 Bs + (i * 32 + wave * 4) * 128);
    }
    __syncthreads();
#pragma unroll
    for (int kk = 0; kk < 128; kk += 32) {
      s16x8 af[2], bfr[4];
#pragma unroll
      for (int i = 0; i < 2; ++i)
        af[i] = *(const s16x8*)(As + (wm * 32 + i * 16 + (lane & 15)) * 128 + kk + (lane >> 4) * 8);
#pragma unroll
      for (int j = 0; j < 4; ++j)
        bfr[j] = *(const s16x8*)(Bs + (wn * 64 + j * 16 + (lane & 15)) * 128 + kk + (lane >> 4) * 8);
#pragma unroll
      for (int i = 0; i < 2; ++i)
#pragma unroll
        for (int j = 0; j < 4; ++j)
          acc[i][j] = __builtin_amdgcn_mfma_f32_16x16x32_bf16(af[i], bfr[j], acc[i][j], 0, 0, 0);
    }
  }
  const int n_base = n0 + wn * 64;
#pragma unroll
  for (int i = 0; i < 2; ++i) {
    int grow = m0 + wm * 32 + i * 16 + (lane >> 4) * 4;
#pragma unroll
    for (int j = 0; j < 4; ++j) {
      int gcol = n_base + j * 16 + (lane & 15);
      unsigned short* dst;
      float scale;
      if (gcol < 512) { dst = Qws; scale = 0.125f; }        // q, fold SCALE (exact pow2)
      else            { dst = Kws; gcol -= 512; scale = 1.0f; }
#pragma unroll
      for (int r = 0; r < 4; ++r)
        dst[(size_t)(grow + r) * 512 + gcol] = f2bf(acc[i][j][r] * scale);
    }
  }
}

// ---------------- 3) KV partials: KVp[b][h][chunk][dq][l] = sum_{n in chunk} k*v  (f32)
__global__ void k_kv_partial(const unsigned short* __restrict__ Kws,
                             const float* __restrict__ v,   // [2048][512] f32, col h*64+l
                             float* __restrict__ KVp) {
  const int wg = blockIdx.x;      // b*128 + h*16 + chunk
  const int chunk = wg & 15;
  const int h = (wg >> 4) & 7;
  const int b = wg >> 7;
  __shared__ unsigned short Ks[128 * 64];  // 16 KB bf16
  __shared__ float Vs[128 * 64];           // 32 KB f32
  const int tid = threadIdx.x;
  const int lane = tid & 63;
  const int wave = tid >> 6;
  const int n0 = chunk * 128;
  // K staging: 8 lanes/row (16B = 8 bf16), 8 rows/call, 4 calls -> 32 rows/wave
  {
    const int r = wave * 32 + (lane >> 3);
    const int c = (lane & 7) * 8;
#pragma unroll
    for (int i = 0; i < 4; ++i)
      async_cp16(Kws + (size_t)(b * 2048 + n0 + r + i * 8) * 512 + h * 64 + c,
                 Ks + (wave * 32 + i * 8) * 64);
  }
  // V staging (f32): 16 lanes/row (16B = 4 f32), 4 rows/call, 8 calls -> 32 rows/wave
  {
    const int r = wave * 32 + (lane >> 4);
    const int c = (lane & 15) * 4;
#pragma unroll
    for (int i = 0; i < 8; ++i)
      async_cp16(v + (size_t)(n0 + r + i * 4) * 512 + h * 64 + c,
                 Vs + (wave * 32 + i * 4) * 64);
  }
  __syncthreads();
  const int dq0 = (tid & 15) * 4;
  const int l0 = (tid >> 4) * 4;
  float acc[4][4] = {};
#pragma unroll 4
  for (int n = 0; n < 128; ++n) {
    ushort4 ku = *(const ushort4*)(Ks + n * 64 + dq0);
    f32x4 va = *(const f32x4*)(Vs + n * 64 + l0);
    float ka[4] = {bf2f(ku.x), bf2f(ku.y), bf2f(ku.z), bf2f(ku.w)};
#pragma unroll
    for (int a = 0; a < 4; ++a)
#pragma unroll
      for (int c = 0; c < 4; ++c)
        acc[a][c] += ka[a] * va[c];
  }
  float* dst = KVp + (size_t)wg * 4096;
#pragma unroll
  for (int a = 0; a < 4; ++a) {
    f32x4 o;
    o[0] = acc[a][0]; o[1] = acc[a][1]; o[2] = acc[a][2]; o[3] = acc[a][3];
    *(f32x4*)(dst + (dq0 + a) * 64 + l0) = o;
  }
}

// ---------------- 4) reduce + W = KV@proj_h -> WcatT[b][dout][h*64+dq] (bf16)
// 256 blocks (bh x 8 dq-groups): full-chip reduce of the 8.4MB partials
__global__ void k_w(const float* __restrict__ KVp,
                    const float* __restrict__ proj,   // [512][64] f32
                    unsigned short* __restrict__ WcatT) {  // [B][64][512]
  const int blk = blockIdx.x;   // bh*8 + g
  const int g = blk & 7;        // dq-group: dq = g*8 .. g*8+7
  const int bh = blk >> 3;
  const int h = bh & 7;
  const int b = bh >> 3;
  __shared__ float kv[8 * 64];     // [dq_local][l]
  __shared__ float pj[64 * 64];    // [l][dout]
  const int tid = threadIdx.x;
  {  // reduce 16 chunks for this block's 512-element slice (2 elems/thread)
    const int e = tid * 2;
    const float* src = KVp + (size_t)bh * 16 * 4096 + g * 512 + e;
    float s0 = 0.f, s1 = 0.f;
#pragma unroll
    for (int c = 0; c < 16; ++c) {
      float2 t = *(const float2*)(src + c * 4096);
      s0 += t.x; s1 += t.y;
    }
    kv[e] = s0; kv[e + 1] = s1;
  }
#pragma unroll
  for (int j = 0; j < 16; ++j) {  // stage proj head h: rows h*64..h*64+63 (contiguous 16KB)
    int e = tid + j * 256;
    pj[e] = proj[(size_t)h * 4096 + e];
  }
  __syncthreads();
  const int dout = tid & 63;
  const int dq0 = tid >> 6;    // 0..3; thread also does dq0+4
  float w0 = 0.f, w1 = 0.f;
  for (int l = 0; l < 64; ++l) {
    float p = pj[l * 64 + dout];
    w0 += kv[dq0 * 64 + l] * p;
    w1 += kv[(dq0 + 4) * 64 + l] * p;
  }
  const int dqb = h * 64 + g * 8;
  WcatT[(size_t)(b * 64 + dout) * 512 + dqb + dq0] = f2bf(w0);
  WcatT[(size_t)(b * 64 + dout) * 512 + dqb + dq0 + 4] = f2bf(w1);
}

// ---------------- 5) GEMM2 streaming: out[b] = Qws[b](2048x512) @ WcatT[b]^T(512x64)
// 512 blocks x 1 wave; 16-row m-tile per wave; no LDS, no barriers. All operands L2-hot.
__global__ __launch_bounds__(64) void k_gemm2(
    const unsigned short* __restrict__ Qws,
    const unsigned short* __restrict__ WcatT,
    float* __restrict__ out) {   // [8192][64] f32
  const int m0 = blockIdx.x * 16;
  const int lane = threadIdx.x;
  const unsigned short* Bb = WcatT + (size_t)(m0 >> 11) * 64 * 512;
  const int arow = lane & 15;
  const int koff = (lane >> 4) * 8;
  f32x4 acc[4] = {};
#pragma unroll
  for (int kk = 0; kk < 16; ++kk) {
    s16x8 af = *(const s16x8*)(Qws + (size_t)(m0 + arow) * 512 + kk * 32 + koff);
#pragma unroll
    for (int j = 0; j < 4; ++j) {
      s16x8 bf = *(const s16x8*)(Bb + (size_t)(j * 16 + arow) * 512 + kk * 32 + koff);
      acc[j] = __builtin_amdgcn_mfma_f32_16x16x32_bf16(af, bf, acc[j], 0, 0, 0);
    }
  }
  const int grow = m0 + (lane >> 4) * 4;
#pragma unroll
  for (int j = 0; j < 4; ++j) {
    int gcol = j * 16 + arow;
#pragma unroll
    for (int r = 0; r < 4; ++r)
      out[(size_t)(grow + r) * 64 + gcol] = acc[j][r];
  }
}

extern "C" void kernel_launch(void* const* d_in, const int* in_sizes, int n_in,
                              void* d_out, int out_size, void* d_ws, size_t ws_size,
                              hipStream_t stream) {
  const float* x    = (const float*)d_in[0];  // [4][2048][512] f32
  const float* v    = (const float*)d_in[1];  // [2048][8][64]  f32
  const float* qkv  = (const float*)d_in[2];  // [512][1024]    f32
  const float* proj = (const float*)d_in[3];  // [512][64]      f32
  float* out = (float*)d_out;                 // [4][2048][64]  f32

  char* ws = (char*)d_ws;
  unsigned short* xb   = (unsigned short*)ws; ws += (size_t)8192 * 512 * 2;  // 8.4 MB
  unsigned short* qkvT = (unsigned short*)ws; ws += (size_t)1024 * 512 * 2;  // 1 MB
  unsigned short* Qws  = (unsigned short*)ws; ws += (size_t)8192 * 512 * 2;  // 8.4 MB
  unsigned short* Kws  = (unsigned short*)ws; ws += (size_t)8192 * 512 * 2;  // 8.4 MB
  float*          KVp  = (float*)ws;          ws += (size_t)512 * 4096 * 4;  // 8.4 MB
  unsigned short* Wc   = (unsigned short*)ws; ws += (size_t)4 * 64 * 512 * 2;

  hipLaunchKernelGGL(k_prep, dim3(2560), dim3(256), 0, stream, x, qkv, xb, qkvT);
  hipLaunchKernelGGL(k_gemm1, dim3(512), dim3(512), 0, stream, xb, qkvT, Qws, Kws);
  hipLaunchKernelGGL(k_kv_partial, dim3(512), dim3(256), 0, stream, Kws, v, KVp);
  hipLaunchKernelGGL(k_w, dim3(256), dim3(256), 0, stream, KVp, proj, Wc);
  hipLaunchKernelGGL(k_gemm2, dim3(512), dim3(64), 0, stream, Qws, Wc, out);
}

// Round 8
// 112.092 us; speedup vs baseline: 1.2410x; 1.1013x over previous
//
#include <hip/hip_runtime.h>
#include <hip/hip_bf16.h>

// Problem: B=4, N=2048, C=512, H=8, D=64, L=64, SCALE=0.125. Inputs f32, output f32.
// No softmax => attention is linear => reassociate:
//   out[b] = (x[b]@Wq * SCALE)(2048x512) @ Wcat[b](512x64)
//   Wcat[b][h*64+dq][:] = ( sum_m k[b,m,h,dq] * v[m,h,:] ) @ proj_h
// R8 = R5 + (a) gemm1 reads x f32 directly (reg-stage A, no xb buffer), (b) KVp bf16.

using f32x4 = __attribute__((ext_vector_type(4))) float;
using s16x8 = __attribute__((ext_vector_type(8))) short;  // 8 bf16 (4 VGPRs), MFMA operand

__device__ __forceinline__ unsigned short f2bf(float f) {
  unsigned int i;
  __builtin_memcpy(&i, &f, 4);
  unsigned int lsb = (i >> 16) & 1u;
  i += 0x7fffu + lsb;  // round-to-nearest-even
  return (unsigned short)(i >> 16);
}
__device__ __forceinline__ float bf2f(unsigned short u) {
  unsigned int i = ((unsigned int)u) << 16;
  float f;
  __builtin_memcpy(&f, &i, 4);
  return f;
}
__device__ __forceinline__ ushort4 pk4(f32x4 a) {
  ushort4 u;
  u.x = f2bf(a[0]); u.y = f2bf(a[1]); u.z = f2bf(a[2]); u.w = f2bf(a[3]);
  return u;
}
__device__ __forceinline__ void async_cp16(const void* g, void* l) {
  // 16B global->LDS DMA; LDS dest must be WAVE-UNIFORM base (HW adds lane*16)
  __builtin_amdgcn_global_load_lds((const __attribute__((address_space(1))) void*)g,
                                   (__attribute__((address_space(3))) void*)l, 16, 0, 0);
}

// ---------------- 1) prep: transpose qkv only (512 blocks)
// qkvT[s*512+h*64+d][c] = qkv[c][h*128+s*64+d]
__global__ void k_prep(const float* __restrict__ qkv, unsigned short* __restrict__ qkvT) {
  __shared__ float tile[32][33];
  const int idx = blockIdx.x;
  const int tid = threadIdx.x;
  const int j0 = (idx & 31) * 32;
  const int c0 = (idx >> 5) * 32;
  const int tx = tid & 31, ty = tid >> 5;  // 32 x 8
#pragma unroll
  for (int i = 0; i < 32; i += 8)
    tile[ty + i][tx] = qkv[(size_t)(c0 + ty + i) * 1024 + j0 + tx];
  __syncthreads();
  const int h = j0 >> 7, s = (j0 >> 6) & 1, d0 = j0 & 63;
  const int jp0 = s * 512 + h * 64 + d0;
#pragma unroll
  for (int i = 0; i < 32; i += 8)
    qkvT[(size_t)(jp0 + ty + i) * 512 + c0 + tx] = f2bf(tile[tx][ty + i]);
}

// ---------------- 2) GEMM1 (8 waves, BK=64, XCD-swizzled): x(f32) @ qkvT^T -> Q (scaled), K
// A: reg-staged from f32 x with convert + padded ds_write (issue-early prefetch).
// B: global_load_lds (linear). Swizzle: XCD k owns 8 m-panels x all 8 n-panels -> L2-fit.
__global__ __launch_bounds__(512) void k_gemm1(
    const float* __restrict__ X,            // x [8192][512] f32
    const unsigned short* __restrict__ Bt,  // qkvT [1024][512] bf16
    unsigned short* __restrict__ Qws,       // [8192][512] col = h*64+d
    unsigned short* __restrict__ Kws) {     // [8192][512]
  __shared__ unsigned short As[128 * 80];   // pad 80: 160B rows, 16B-aligned, bank-spread
  __shared__ unsigned short Bs[128 * 64];
  const int lin = blockIdx.x;
  const int wg = (lin & 7) * 64 + (lin >> 3);   // bijective: 512 = 8 XCDs x 64
  const int m0 = (wg >> 3) * 128;
  const int n0 = (wg & 7) * 128;
  const int tid = threadIdx.x;
  const int lane = tid & 63;
  const int wave = tid >> 6;       // 8 waves: wm 4 x wn 2
  const int wm = wave >> 1, wn = wave & 1;

  f32x4 acc[2][4] = {};

  // A-stage mapping: 16 threads/row (16B f32x4), 32 rows/call, 4 calls
  const int arow_s = tid >> 4;        // 0..31
  const int acol_s = (tid & 15) * 4;  // f32 col
  // B-stage mapping (gload_lds): 8 lanes/row (16B = 8 bf16), 8 rows/call/wave
  const int rlane = lane >> 3;
  const int clane = (lane & 7) * 8;

  f32x4 areg[4];
#pragma unroll
  for (int i = 0; i < 4; ++i)
    areg[i] = *(const f32x4*)(X + (size_t)(m0 + i * 32 + arow_s) * 512 + acol_s);

  for (int kt = 0; kt < 512; kt += 64) {
    __syncthreads();
    // B async stage for this kt
#pragma unroll
    for (int i = 0; i < 2; ++i)
      async_cp16(Bt + (size_t)(n0 + i * 64 + wave * 8 + rlane) * 512 + kt + clane,
                 Bs + (i * 64 + wave * 8) * 64);
    // A: convert prefetched regs -> LDS (8B stores, conflict-free via stride 80)
#pragma unroll
    for (int i = 0; i < 4; ++i)
      *(ushort4*)(As + (i * 32 + arow_s) * 80 + acol_s) = pk4(areg[i]);
    __syncthreads();
    // issue next tile's A loads AFTER the barrier so they aren't drained by it;
    // they complete under the MFMA loop below.
    if (kt + 64 < 512) {
#pragma unroll
      for (int i = 0; i < 4; ++i)
        areg[i] = *(const f32x4*)(X + (size_t)(m0 + i * 32 + arow_s) * 512 + kt + 64 + acol_s);
    }
#pragma unroll
    for (int kk = 0; kk < 64; kk += 32) {
      s16x8 af[2], bfr[4];
#pragma unroll
      for (int i = 0; i < 2; ++i)
        af[i] = *(const s16x8*)(As + (wm * 32 + i * 16 + (lane & 15)) * 80 + kk + (lane >> 4) * 8);
#pragma unroll
      for (int j = 0; j < 4; ++j)
        bfr[j] = *(const s16x8*)(Bs + (wn * 64 + j * 16 + (lane & 15)) * 64 + kk + (lane >> 4) * 8);
#pragma unroll
      for (int i = 0; i < 2; ++i)
#pragma unroll
        for (int j = 0; j < 4; ++j)
          acc[i][j] = __builtin_amdgcn_mfma_f32_16x16x32_bf16(af[i], bfr[j], acc[i][j], 0, 0, 0);
    }
  }
  const int n_base = n0 + wn * 64;
#pragma unroll
  for (int i = 0; i < 2; ++i) {
    int grow = m0 + wm * 32 + i * 16 + (lane >> 4) * 4;
#pragma unroll
    for (int j = 0; j < 4; ++j) {
      int gcol = n_base + j * 16 + (lane & 15);
      unsigned short* dst;
      float scale;
      if (gcol < 512) { dst = Qws; scale = 0.125f; }        // q, fold SCALE (exact pow2)
      else            { dst = Kws; gcol -= 512; scale = 1.0f; }
#pragma unroll
      for (int r = 0; r < 4; ++r)
        dst[(size_t)(grow + r) * 512 + gcol] = f2bf(acc[i][j][r] * scale);
    }
  }
}

// ---------------- 3) KV partials: KVp[b][h][chunk][dq][l] = sum_{n in chunk} k*v  (bf16 out)
__global__ void k_kv_partial(const unsigned short* __restrict__ Kws,
                             const float* __restrict__ v,   // [2048][512] f32, col h*64+l
                             unsigned short* __restrict__ KVp) {
  const int wg = blockIdx.x;      // b*128 + h*16 + chunk
  const int chunk = wg & 15;
  const int h = (wg >> 4) & 7;
  const int b = wg >> 7;
  __shared__ unsigned short Ks[128 * 64];  // 16 KB bf16
  __shared__ float Vs[128 * 64];           // 32 KB f32
  const int tid = threadIdx.x;
  const int lane = tid & 63;
  const int wave = tid >> 6;
  const int n0 = chunk * 128;
  // K staging: 8 lanes/row (16B = 8 bf16), 8 rows/call, 4 calls -> 32 rows/wave
  {
    const int r = wave * 32 + (lane >> 3);
    const int c = (lane & 7) * 8;
#pragma unroll
    for (int i = 0; i < 4; ++i)
      async_cp16(Kws + (size_t)(b * 2048 + n0 + r + i * 8) * 512 + h * 64 + c,
                 Ks + (wave * 32 + i * 8) * 64);
  }
  // V staging (f32): 16 lanes/row (16B = 4 f32), 4 rows/call, 8 calls -> 32 rows/wave
  {
    const int r = wave * 32 + (lane >> 4);
    const int c = (lane & 15) * 4;
#pragma unroll
    for (int i = 0; i < 8; ++i)
      async_cp16(v + (size_t)(n0 + r + i * 4) * 512 + h * 64 + c,
                 Vs + (wave * 32 + i * 4) * 64);
  }
  __syncthreads();
  const int dq0 = (tid & 15) * 4;
  const int l0 = (tid >> 4) * 4;
  float acc[4][4] = {};
#pragma unroll 4
  for (int n = 0; n < 128; ++n) {
    ushort4 ku = *(const ushort4*)(Ks + n * 64 + dq0);
    f32x4 va = *(const f32x4*)(Vs + n * 64 + l0);
    float ka[4] = {bf2f(ku.x), bf2f(ku.y), bf2f(ku.z), bf2f(ku.w)};
#pragma unroll
    for (int a = 0; a < 4; ++a)
#pragma unroll
      for (int c = 0; c < 4; ++c)
        acc[a][c] += ka[a] * va[c];
  }
  unsigned short* dst = KVp + (size_t)wg * 4096;
#pragma unroll
  for (int a = 0; a < 4; ++a) {
    f32x4 o;
    o[0] = acc[a][0]; o[1] = acc[a][1]; o[2] = acc[a][2]; o[3] = acc[a][3];
    *(ushort4*)(dst + (dq0 + a) * 64 + l0) = pk4(o);
  }
}

// ---------------- 4) reduce + W = KV@proj_h -> WcatT[b][dout][h*64+dq] (bf16)
// 256 blocks (bh x 8 dq-groups): full-chip reduce of the 4.2MB bf16 partials
__global__ void k_w(const unsigned short* __restrict__ KVp,
                    const float* __restrict__ proj,   // [512][64] f32
                    unsigned short* __restrict__ WcatT) {  // [B][64][512]
  const int blk = blockIdx.x;   // bh*8 + g
  const int g = blk & 7;        // dq-group: dq = g*8 .. g*8+7
  const int bh = blk >> 3;
  const int h = bh & 7;
  const int b = bh >> 3;
  __shared__ float kv[8 * 64];     // [dq_local][l]
  __shared__ float pj[64 * 64];    // [l][dout]
  const int tid = threadIdx.x;
  {  // reduce 16 chunks for this block's 512-element slice (2 elems/thread)
    const int e = tid * 2;
    const unsigned short* src = KVp + (size_t)bh * 16 * 4096 + g * 512 + e;
    float s0 = 0.f, s1 = 0.f;
#pragma unroll
    for (int c = 0; c < 16; ++c) {
      ushort2 t = *(const ushort2*)(src + c * 4096);
      s0 += bf2f(t.x); s1 += bf2f(t.y);
    }
    kv[e] = s0; kv[e + 1] = s1;
  }
#pragma unroll
  for (int j = 0; j < 16; ++j) {  // stage proj head h: rows h*64..h*64+63 (contiguous 16KB)
    int e = tid + j * 256;
    pj[e] = proj[(size_t)h * 4096 + e];
  }
  __syncthreads();
  const int dout = tid & 63;
  const int dq0 = tid >> 6;    // 0..3; thread also does dq0+4
  float w0 = 0.f, w1 = 0.f;
  for (int l = 0; l < 64; ++l) {
    float p = pj[l * 64 + dout];
    w0 += kv[dq0 * 64 + l] * p;
    w1 += kv[(dq0 + 4) * 64 + l] * p;
  }
  const int dqb = h * 64 + g * 8;
  WcatT[(size_t)(b * 64 + dout) * 512 + dqb + dq0] = f2bf(w0);
  WcatT[(size_t)(b * 64 + dout) * 512 + dqb + dq0 + 4] = f2bf(w1);
}

// ---------------- 5) GEMM2 streaming: out[b] = Qws[b](2048x512) @ WcatT[b]^T(512x64)
// 512 blocks x 1 wave; 16-row m-tile per wave; no LDS, no barriers. All operands L2-hot.
__global__ __launch_bounds__(64) void k_gemm2(
    const unsigned short* __restrict__ Qws,
    const unsigned short* __restrict__ WcatT,
    float* __restrict__ out) {   // [8192][64] f32
  const int m0 = blockIdx.x * 16;
  const int lane = threadIdx.x;
  const unsigned short* Bb = WcatT + (size_t)(m0 >> 11) * 64 * 512;
  const int arow = lane & 15;
  const int koff = (lane >> 4) * 8;
  f32x4 acc[4] = {};
#pragma unroll
  for (int kk = 0; kk < 16; ++kk) {
    s16x8 af = *(const s16x8*)(Qws + (size_t)(m0 + arow) * 512 + kk * 32 + koff);
#pragma unroll
    for (int j = 0; j < 4; ++j) {
      s16x8 bf = *(const s16x8*)(Bb + (size_t)(j * 16 + arow) * 512 + kk * 32 + koff);
      acc[j] = __builtin_amdgcn_mfma_f32_16x16x32_bf16(af, bf, acc[j], 0, 0, 0);
    }
  }
  const int grow = m0 + (lane >> 4) * 4;
#pragma unroll
  for (int j = 0; j < 4; ++j) {
    int gcol = j * 16 + arow;
#pragma unroll
    for (int r = 0; r < 4; ++r)
      out[(size_t)(grow + r) * 64 + gcol] = acc[j][r];
  }
}

extern "C" void kernel_launch(void* const* d_in, const int* in_sizes, int n_in,
                              void* d_out, int out_size, void* d_ws, size_t ws_size,
                              hipStream_t stream) {
  const float* x    = (const float*)d_in[0];  // [4][2048][512] f32
  const float* v    = (const float*)d_in[1];  // [2048][8][64]  f32
  const float* qkv  = (const float*)d_in[2];  // [512][1024]    f32
  const float* proj = (const float*)d_in[3];  // [512][64]      f32
  float* out = (float*)d_out;                 // [4][2048][64]  f32

  char* ws = (char*)d_ws;
  unsigned short* qkvT = (unsigned short*)ws; ws += (size_t)1024 * 512 * 2;  // 1 MB
  unsigned short* Qws  = (unsigned short*)ws; ws += (size_t)8192 * 512 * 2;  // 8.4 MB
  unsigned short* Kws  = (unsigned short*)ws; ws += (size_t)8192 * 512 * 2;  // 8.4 MB
  unsigned short* KVp  = (unsigned short*)ws; ws += (size_t)512 * 4096 * 2;  // 4.2 MB
  unsigned short* Wc   = (unsigned short*)ws; ws += (size_t)4 * 64 * 512 * 2;

  hipLaunchKernelGGL(k_prep, dim3(512), dim3(256), 0, stream, qkv, qkvT);
  hipLaunchKernelGGL(k_gemm1, dim3(512), dim3(512), 0, stream, x, qkvT, Qws, Kws);
  hipLaunchKernelGGL(k_kv_partial, dim3(512), dim3(256), 0, stream, Kws, v, KVp);
  hipLaunchKernelGGL(k_w, dim3(256), dim3(256), 0, stream, KVp, proj, Wc);
  hipLaunchKernelGGL(k_gemm2, dim3(512), dim3(64), 0, stream, Qws, Wc, out);
}

// Round 9
// 111.958 us; speedup vs baseline: 1.2425x; 1.0012x over previous
//
#include <hip/hip_runtime.h>
#include <hip/hip_bf16.h>

// Problem: B=4, N=2048, C=512, H=8, D=64, L=64, SCALE=0.125. Inputs f32, output f32.
// No softmax => attention is linear => reassociate:
//   out[b] = (x[b]@Wq * SCALE)(2048x512) @ Wcat[b](512x64)
//   Wcat[b][h*64+dq][:] = ( sum_m k[b,m,h,dq] * v[m,h,:] ) @ proj_h
// R9 = R8 + gemm1 T3/T4 pipeline: double-buffered B (global_load_lds) with counted
// s_waitcnt vmcnt(6) + raw s_barrier (never drain to 0 in the main loop).

using f32x4 = __attribute__((ext_vector_type(4))) float;
using s16x8 = __attribute__((ext_vector_type(8))) short;  // 8 bf16 (4 VGPRs), MFMA operand

__device__ __forceinline__ unsigned short f2bf(float f) {
  unsigned int i;
  __builtin_memcpy(&i, &f, 4);
  unsigned int lsb = (i >> 16) & 1u;
  i += 0x7fffu + lsb;  // round-to-nearest-even
  return (unsigned short)(i >> 16);
}
__device__ __forceinline__ float bf2f(unsigned short u) {
  unsigned int i = ((unsigned int)u) << 16;
  float f;
  __builtin_memcpy(&f, &i, 4);
  return f;
}
__device__ __forceinline__ ushort4 pk4(f32x4 a) {
  ushort4 u;
  u.x = f2bf(a[0]); u.y = f2bf(a[1]); u.z = f2bf(a[2]); u.w = f2bf(a[3]);
  return u;
}
__device__ __forceinline__ void async_cp16(const void* g, void* l) {
  // 16B global->LDS DMA; LDS dest must be WAVE-UNIFORM base (HW adds lane*16)
  __builtin_amdgcn_global_load_lds((const __attribute__((address_space(1))) void*)g,
                                   (__attribute__((address_space(3))) void*)l, 16, 0, 0);
}

// ---------------- 1) prep: transpose qkv only (512 blocks)
// qkvT[s*512+h*64+d][c] = qkv[c][h*128+s*64+d]
__global__ void k_prep(const float* __restrict__ qkv, unsigned short* __restrict__ qkvT) {
  __shared__ float tile[32][33];
  const int idx = blockIdx.x;
  const int tid = threadIdx.x;
  const int j0 = (idx & 31) * 32;
  const int c0 = (idx >> 5) * 32;
  const int tx = tid & 31, ty = tid >> 5;  // 32 x 8
#pragma unroll
  for (int i = 0; i < 32; i += 8)
    tile[ty + i][tx] = qkv[(size_t)(c0 + ty + i) * 1024 + j0 + tx];
  __syncthreads();
  const int h = j0 >> 7, s = (j0 >> 6) & 1, d0 = j0 & 63;
  const int jp0 = s * 512 + h * 64 + d0;
#pragma unroll
  for (int i = 0; i < 32; i += 8)
    qkvT[(size_t)(jp0 + ty + i) * 512 + c0 + tx] = f2bf(tile[tx][ty + i]);
}

// ---------------- 2) GEMM1 (8 waves, BK=64, XCD-swizzled, pipelined): x(f32)@qkvT^T -> Q,K
// A: reg-staged f32->bf16 (issue-early prefetch), padded LDS stride 80.
// B: global_load_lds double-buffered; counted vmcnt keeps prefetches in flight across
// barriers (T3+T4). Per-wave accounting entering tile t: outstanding = 2xB(t+1) +
// 4xAreg(t+1) = 6 newer ops -> s_waitcnt vmcnt(6) guarantees B(t) complete.
__global__ __launch_bounds__(512) void k_gemm1(
    const float* __restrict__ X,            // x [8192][512] f32
    const unsigned short* __restrict__ Bt,  // qkvT [1024][512] bf16
    unsigned short* __restrict__ Qws,       // [8192][512] col = h*64+d
    unsigned short* __restrict__ Kws) {     // [8192][512]
  __shared__ unsigned short As[128 * 80];     // 20 KB, pad 80 for bank spread
  __shared__ unsigned short Bs[2][128 * 64];  // 2 x 16 KB
  const int lin = blockIdx.x;
  const int wg = (lin & 7) * 64 + (lin >> 3);   // bijective: 512 = 8 XCDs x 64
  const int m0 = (wg >> 3) * 128;
  const int n0 = (wg & 7) * 128;
  const int tid = threadIdx.x;
  const int lane = tid & 63;
  const int wave = tid >> 6;       // 8 waves: wm 4 x wn 2
  const int wm = wave >> 1, wn = wave & 1;

  f32x4 acc[2][4] = {};

  const int arow_s = tid >> 4;        // A-stage: 16 thr/row (16B f32x4), 32 rows/pass
  const int acol_s = (tid & 15) * 4;
  const int rlane = lane >> 3;        // B-stage: 8 lanes/row (16B), 8 rows/call/wave
  const int clane = (lane & 7) * 8;

#define ISSUE_B(buf, kt)                                                                \
  {                                                                                     \
    _Pragma("unroll") for (int i = 0; i < 2; ++i)                                       \
        async_cp16(Bt + (size_t)(n0 + i * 64 + wave * 8 + rlane) * 512 + (kt) + clane,  \
                   Bs[buf] + (i * 64 + wave * 8) * 64);                                 \
  }
#define LOAD_AREG(kt)                                                                   \
  {                                                                                     \
    _Pragma("unroll") for (int i = 0; i < 4; ++i)                                       \
        areg[i] = *(const f32x4*)(X + (size_t)(m0 + i * 32 + arow_s) * 512 + (kt) +     \
                                  acol_s);                                              \
  }
#define WRITE_AS()                                                                      \
  {                                                                                     \
    _Pragma("unroll") for (int i = 0; i < 4; ++i)                                       \
        *(ushort4*)(As + (i * 32 + arow_s) * 80 + acol_s) = pk4(areg[i]);               \
  }

  f32x4 areg[4];
  // prologue: B(0), A(0) -> As, then B(1)/A(1) in flight
  ISSUE_B(0, 0);
  LOAD_AREG(0);
  WRITE_AS();          // compiler inserts vmcnt wait for areg only
  ISSUE_B(1, 64);
  LOAD_AREG(64);

#pragma unroll
  for (int t = 0; t < 8; ++t) {
    if (t < 7)
      asm volatile("s_waitcnt vmcnt(6) lgkmcnt(0)" ::: "memory");
    else
      asm volatile("s_waitcnt vmcnt(0) lgkmcnt(0)" ::: "memory");
    __builtin_amdgcn_s_barrier();
    __builtin_amdgcn_sched_barrier(0);
#pragma unroll
    for (int kk = 0; kk < 64; kk += 32) {
      s16x8 af[2], bfr[4];
#pragma unroll
      for (int i = 0; i < 2; ++i)
        af[i] = *(const s16x8*)(As + (wm * 32 + i * 16 + (lane & 15)) * 80 + kk + (lane >> 4) * 8);
#pragma unroll
      for (int j = 0; j < 4; ++j)
        bfr[j] = *(const s16x8*)(Bs[t & 1] + (wn * 64 + j * 16 + (lane & 15)) * 64 + kk + (lane >> 4) * 8);
#pragma unroll
      for (int i = 0; i < 2; ++i)
#pragma unroll
        for (int j = 0; j < 4; ++j)
          acc[i][j] = __builtin_amdgcn_mfma_f32_16x16x32_bf16(af[i], bfr[j], acc[i][j], 0, 0, 0);
    }
    if (t < 7) {
      __builtin_amdgcn_s_barrier();   // all waves done reading As(t), Bs[t&1]
      WRITE_AS();                     // As <- t+1 (waits areg via compiler)
      if (t < 6) {
        ISSUE_B(t & 1, (t + 2) * 64); // into the buffer just freed
        LOAD_AREG((t + 2) * 64);
      }
    }
  }
#undef ISSUE_B
#undef LOAD_AREG
#undef WRITE_AS

  const int n_base = n0 + wn * 64;
#pragma unroll
  for (int i = 0; i < 2; ++i) {
    int grow = m0 + wm * 32 + i * 16 + (lane >> 4) * 4;
#pragma unroll
    for (int j = 0; j < 4; ++j) {
      int gcol = n_base + j * 16 + (lane & 15);
      unsigned short* dst;
      float scale;
      if (gcol < 512) { dst = Qws; scale = 0.125f; }        // q, fold SCALE (exact pow2)
      else            { dst = Kws; gcol -= 512; scale = 1.0f; }
#pragma unroll
      for (int r = 0; r < 4; ++r)
        dst[(size_t)(grow + r) * 512 + gcol] = f2bf(acc[i][j][r] * scale);
    }
  }
}

// ---------------- 3) KV partials: KVp[b][h][chunk][dq][l] = sum_{n in chunk} k*v  (bf16 out)
__global__ void k_kv_partial(const unsigned short* __restrict__ Kws,
                             const float* __restrict__ v,   // [2048][512] f32, col h*64+l
                             unsigned short* __restrict__ KVp) {
  const int wg = blockIdx.x;      // b*128 + h*16 + chunk
  const int chunk = wg & 15;
  const int h = (wg >> 4) & 7;
  const int b = wg >> 7;
  __shared__ unsigned short Ks[128 * 64];  // 16 KB bf16
  __shared__ float Vs[128 * 64];           // 32 KB f32
  const int tid = threadIdx.x;
  const int lane = tid & 63;
  const int wave = tid >> 6;
  const int n0 = chunk * 128;
  // K staging: 8 lanes/row (16B = 8 bf16), 8 rows/call, 4 calls -> 32 rows/wave
  {
    const int r = wave * 32 + (lane >> 3);
    const int c = (lane & 7) * 8;
#pragma unroll
    for (int i = 0; i < 4; ++i)
      async_cp16(Kws + (size_t)(b * 2048 + n0 + r + i * 8) * 512 + h * 64 + c,
                 Ks + (wave * 32 + i * 8) * 64);
  }
  // V staging (f32): 16 lanes/row (16B = 4 f32), 4 rows/call, 8 calls -> 32 rows/wave
  {
    const int r = wave * 32 + (lane >> 4);
    const int c = (lane & 15) * 4;
#pragma unroll
    for (int i = 0; i < 8; ++i)
      async_cp16(v + (size_t)(n0 + r + i * 4) * 512 + h * 64 + c,
                 Vs + (wave * 32 + i * 4) * 64);
  }
  __syncthreads();
  const int dq0 = (tid & 15) * 4;
  const int l0 = (tid >> 4) * 4;
  float acc[4][4] = {};
#pragma unroll 4
  for (int n = 0; n < 128; ++n) {
    ushort4 ku = *(const ushort4*)(Ks + n * 64 + dq0);
    f32x4 va = *(const f32x4*)(Vs + n * 64 + l0);
    float ka[4] = {bf2f(ku.x), bf2f(ku.y), bf2f(ku.z), bf2f(ku.w)};
#pragma unroll
    for (int a = 0; a < 4; ++a)
#pragma unroll
      for (int c = 0; c < 4; ++c)
        acc[a][c] += ka[a] * va[c];
  }
  unsigned short* dst = KVp + (size_t)wg * 4096;
#pragma unroll
  for (int a = 0; a < 4; ++a) {
    f32x4 o;
    o[0] = acc[a][0]; o[1] = acc[a][1]; o[2] = acc[a][2]; o[3] = acc[a][3];
    *(ushort4*)(dst + (dq0 + a) * 64 + l0) = pk4(o);
  }
}

// ---------------- 4) reduce + W = KV@proj_h -> WcatT[b][dout][h*64+dq] (bf16)
// 256 blocks (bh x 8 dq-groups): full-chip reduce of the 4.2MB bf16 partials
__global__ void k_w(const unsigned short* __restrict__ KVp,
                    const float* __restrict__ proj,   // [512][64] f32
                    unsigned short* __restrict__ WcatT) {  // [B][64][512]
  const int blk = blockIdx.x;   // bh*8 + g
  const int g = blk & 7;        // dq-group: dq = g*8 .. g*8+7
  const int bh = blk >> 3;
  const int h = bh & 7;
  const int b = bh >> 3;
  __shared__ float kv[8 * 64];     // [dq_local][l]
  __shared__ float pj[64 * 64];    // [l][dout]
  const int tid = threadIdx.x;
  {  // reduce 16 chunks for this block's 512-element slice (2 elems/thread)
    const int e = tid * 2;
    const unsigned short* src = KVp + (size_t)bh * 16 * 4096 + g * 512 + e;
    float s0 = 0.f, s1 = 0.f;
#pragma unroll
    for (int c = 0; c < 16; ++c) {
      ushort2 t = *(const ushort2*)(src + c * 4096);
      s0 += bf2f(t.x); s1 += bf2f(t.y);
    }
    kv[e] = s0; kv[e + 1] = s1;
  }
#pragma unroll
  for (int j = 0; j < 16; ++j) {  // stage proj head h: rows h*64..h*64+63 (contiguous 16KB)
    int e = tid + j * 256;
    pj[e] = proj[(size_t)h * 4096 + e];
  }
  __syncthreads();
  const int dout = tid & 63;
  const int dq0 = tid >> 6;    // 0..3; thread also does dq0+4
  float w0 = 0.f, w1 = 0.f;
  for (int l = 0; l < 64; ++l) {
    float p = pj[l * 64 + dout];
    w0 += kv[dq0 * 64 + l] * p;
    w1 += kv[(dq0 + 4) * 64 + l] * p;
  }
  const int dqb = h * 64 + g * 8;
  WcatT[(size_t)(b * 64 + dout) * 512 + dqb + dq0] = f2bf(w0);
  WcatT[(size_t)(b * 64 + dout) * 512 + dqb + dq0 + 4] = f2bf(w1);
}

// ---------------- 5) GEMM2 streaming: out[b] = Qws[b](2048x512) @ WcatT[b]^T(512x64)
// 512 blocks x 1 wave; 16-row m-tile per wave; no LDS, no barriers. All operands L2-hot.
__global__ __launch_bounds__(64) void k_gemm2(
    const unsigned short* __restrict__ Qws,
    const unsigned short* __restrict__ WcatT,
    float* __restrict__ out) {   // [8192][64] f32
  const int m0 = blockIdx.x * 16;
  const int lane = threadIdx.x;
  const unsigned short* Bb = WcatT + (size_t)(m0 >> 11) * 64 * 512;
  const int arow = lane & 15;
  const int koff = (lane >> 4) * 8;
  f32x4 acc[4] = {};
#pragma unroll
  for (int kk = 0; kk < 16; ++kk) {
    s16x8 af = *(const s16x8*)(Qws + (size_t)(m0 + arow) * 512 + kk * 32 + koff);
#pragma unroll
    for (int j = 0; j < 4; ++j) {
      s16x8 bf = *(const s16x8*)(Bb + (size_t)(j * 16 + arow) * 512 + kk * 32 + koff);
      acc[j] = __builtin_amdgcn_mfma_f32_16x16x32_bf16(af, bf, acc[j], 0, 0, 0);
    }
  }
  const int grow = m0 + (lane >> 4) * 4;
#pragma unroll
  for (int j = 0; j < 4; ++j) {
    int gcol = j * 16 + arow;
#pragma unroll
    for (int r = 0; r < 4; ++r)
      out[(size_t)(grow + r) * 64 + gcol] = acc[j][r];
  }
}

extern "C" void kernel_launch(void* const* d_in, const int* in_sizes, int n_in,
                              void* d_out, int out_size, void* d_ws, size_t ws_size,
                              hipStream_t stream) {
  const float* x    = (const float*)d_in[0];  // [4][2048][512] f32
  const float* v    = (const float*)d_in[1];  // [2048][8][64]  f32
  const float* qkv  = (const float*)d_in[2];  // [512][1024]    f32
  const float* proj = (const float*)d_in[3];  // [512][64]      f32
  float* out = (float*)d_out;                 // [4][2048][64]  f32

  char* ws = (char*)d_ws;
  unsigned short* qkvT = (unsigned short*)ws; ws += (size_t)1024 * 512 * 2;  // 1 MB
  unsigned short* Qws  = (unsigned short*)ws; ws += (size_t)8192 * 512 * 2;  // 8.4 MB
  unsigned short* Kws  = (unsigned short*)ws; ws += (size_t)8192 * 512 * 2;  // 8.4 MB
  unsigned short* KVp  = (unsigned short*)ws; ws += (size_t)512 * 4096 * 2;  // 4.2 MB
  unsigned short* Wc   = (unsigned short*)ws; ws += (size_t)4 * 64 * 512 * 2;

  hipLaunchKernelGGL(k_prep, dim3(512), dim3(256), 0, stream, qkv, qkvT);
  hipLaunchKernelGGL(k_gemm1, dim3(512), dim3(512), 0, stream, x, qkvT, Qws, Kws);
  hipLaunchKernelGGL(k_kv_partial, dim3(512), dim3(256), 0, stream, Kws, v, KVp);
  hipLaunchKernelGGL(k_w, dim3(256), dim3(256), 0, stream, KVp, proj, Wc);
  hipLaunchKernelGGL(k_gemm2, dim3(512), dim3(64), 0, stream, Qws, Wc, out);
}